// Round 1
// baseline (102.796 us; speedup 1.0000x reference)
//
#include <hip/hip_runtime.h>
#include <math.h>

#define N_NODES 8192
#define F_IN    256
#define F_OUT   128
#define DEG     32
#define ALPHA   0.2f

// ---------------- Kernel A: hW = h @ W  (f32, LDS-staged h rows) -------------
// block = 128 threads (one per output col), each block computes 8 rows.
__global__ void gemm_hw_kernel(const float* __restrict__ h,
                               const float* __restrict__ W,
                               float* __restrict__ hW) {
    __shared__ float hs[8 * F_IN];              // 8 KB
    const int tid  = threadIdx.x;               // 0..127
    const int row0 = blockIdx.x * 8;

    // stage 8 rows of h into LDS with float4 loads (8*256/4 = 512 float4)
    const float4* hsrc = (const float4*)(h + (size_t)row0 * F_IN);
    float4* hdst = (float4*)hs;
    #pragma unroll
    for (int t = 0; t < 4; ++t)
        hdst[tid + t * 128] = hsrc[tid + t * 128];
    __syncthreads();

    float acc[8] = {0.f, 0.f, 0.f, 0.f, 0.f, 0.f, 0.f, 0.f};
    #pragma unroll 4
    for (int k = 0; k < F_IN; ++k) {
        float w = W[k * F_OUT + tid];           // coalesced, L1/L2-hot (128 KB)
        #pragma unroll
        for (int r = 0; r < 8; ++r)
            acc[r] = fmaf(hs[r * F_IN + k], w, acc[r]);  // LDS broadcast
    }
    #pragma unroll
    for (int r = 0; r < 8; ++r)
        hW[(size_t)(row0 + r) * F_OUT + tid] = acc[r];
}

// ---------------- Kernel B: h1 = hW@a[:128], h2 = hW@a[128:] -----------------
// one wave per row
__global__ void h1h2_kernel(const float* __restrict__ hW,
                            const float* __restrict__ a,
                            float* __restrict__ h1,
                            float* __restrict__ h2) {
    const int wave = threadIdx.x >> 6;
    const int lane = threadIdx.x & 63;
    const int row  = blockIdx.x * 4 + wave;
    const float* hr = hW + (size_t)row * F_OUT;

    float s1 = 0.f, s2 = 0.f;
    #pragma unroll
    for (int j = lane; j < F_OUT; j += 64) {
        float v = hr[j];
        s1 = fmaf(v, a[j], s1);
        s2 = fmaf(v, a[F_OUT + j], s2);
    }
    #pragma unroll
    for (int off = 32; off > 0; off >>= 1) {
        s1 += __shfl_down(s1, off);
        s2 += __shfl_down(s2, off);
    }
    if (lane == 0) { h1[row] = s1; h2[row] = s2; }
}

// ---------------- Kernel C: sparse masked softmax + aggregation + ELU --------
// one wave per row; lanes 0..31 = neighbor slots, lane 32 = self entry.
__global__ void attn_kernel(const float* __restrict__ hW,
                            const float* __restrict__ h1,
                            const float* __restrict__ h2,
                            const int*   __restrict__ nbr,
                            float* __restrict__ out) {
    const int wave = threadIdx.x >> 6;
    const int lane = threadIdx.x & 63;
    const int row  = blockIdx.x * 4 + wave;

    int col = -1;
    if (lane < DEG)       col = nbr[(size_t)row * DEG + lane];
    else if (lane == DEG) col = row;

    // dedup + multiplicity over the 33 candidate slots (scatter-add semantics)
    int cnt = 0;          // occurrences among the 32 neighbor slots
    int firstq = lane;    // earliest slot holding this column
    #pragma unroll
    for (int q = 0; q <= DEG; ++q) {
        int cq = __shfl(col, q);
        bool same = (cq == col);
        if (same && q < DEG)    cnt++;
        if (same && q < firstq) firstq = q;
    }
    const bool active = (lane <= DEG) && (col >= 0) && (firstq == lane);

    // mask value: counts/64 + 0.5 on the diagonal
    float mask_val = (float)cnt * (1.0f / 64.0f) + ((col == row) ? 0.5f : 0.0f);

    const float h1row = h1[row];                    // uniform broadcast load
    float h2c = active ? h2[col] : 0.f;
    float s = mask_val * (h1row + h2c);
    float e = (s > 0.f) ? s : ALPHA * s;            // LeakyReLU
    bool valid = active && (e != 0.0f);             // e==0 -> NEG_INF in ref

    // wave softmax over valid lanes
    float ev = valid ? e : -INFINITY;
    #pragma unroll
    for (int off = 32; off > 0; off >>= 1)
        ev = fmaxf(ev, __shfl_xor(ev, off));        // row max
    float w = valid ? expf(e - ev) : 0.f;
    float denom = w;
    #pragma unroll
    for (int off = 32; off > 0; off >>= 1)
        denom += __shfl_xor(denom, off);
    float att = w / denom;                          // 0 for invalid lanes

    // aggregate: all 64 lanes gather 2 features per candidate row of hW
    float acc0 = 0.f, acc1 = 0.f;
    #pragma unroll
    for (int q = 0; q <= DEG; ++q) {
        float aq = __shfl(att, q);
        int   cq = __shfl(col, q);
        if (aq > 0.f) {                              // wave-uniform branch
            const float* hr = hW + (size_t)cq * F_OUT;
            acc0 = fmaf(aq, hr[lane],      acc0);
            acc1 = fmaf(aq, hr[64 + lane], acc1);
        }
    }

    // ELU epilogue
    float o0 = (acc0 > 0.f) ? acc0 : expm1f(acc0);
    float o1 = (acc1 > 0.f) ? acc1 : expm1f(acc1);
    out[(size_t)row * F_OUT + lane]      = o0;
    out[(size_t)row * F_OUT + 64 + lane] = o1;
}

// -----------------------------------------------------------------------------
extern "C" void kernel_launch(void* const* d_in, const int* in_sizes, int n_in,
                              void* d_out, int out_size, void* d_ws, size_t ws_size,
                              hipStream_t stream) {
    const float* h   = (const float*)d_in[0];   // [8192, 256]
    const float* W   = (const float*)d_in[1];   // [256, 128]
    const float* a   = (const float*)d_in[2];   // [256, 1]
    const int*   nbr = (const int*)  d_in[3];   // [8192, 32]
    float* out = (float*)d_out;                 // [8192, 128]

    // workspace layout: hW (4 MB) | h1 (32 KB) | h2 (32 KB)
    float* hW = (float*)d_ws;
    float* h1 = hW + (size_t)N_NODES * F_OUT;
    float* h2 = h1 + N_NODES;

    gemm_hw_kernel<<<N_NODES / 8, 128, 0, stream>>>(h, W, hW);
    h1h2_kernel   <<<N_NODES / 4, 256, 0, stream>>>(hW, a, h1, h2);
    attn_kernel   <<<N_NODES / 4, 256, 0, stream>>>(hW, h1, h2, nbr, out);
}